// Round 7
// baseline (260.830 us; speedup 1.0000x reference)
//
#include <hip/hip_runtime.h>

// Problem constants
#define N_NODES 30000
#define NPAD    30080            // 235 * 128
#define N_EDGES 480000
#define N_RELS  8
#define NB_SCAN 118              // ceil(30000/256)

typedef short bf16x8 __attribute__((ext_vector_type(8)));
typedef float f32x4  __attribute__((ext_vector_type(4)));

__device__ __forceinline__ unsigned short f2bf(float f) {
    unsigned u = __float_as_uint(f);
    u += 0x7fffu + ((u >> 16) & 1u);     // round-to-nearest-even
    return (unsigned short)(u >> 16);
}
__device__ __forceinline__ float bf2f(unsigned short h) {
    return __uint_as_float(((unsigned)h) << 16);
}

__device__ __forceinline__ void load_lds16(const void* g, void* l) {
    __builtin_amdgcn_global_load_lds(
        (const __attribute__((address_space(1))) unsigned int*)g,
        (__attribute__((address_space(3))) unsigned int*)l,
        16, 0, 0);
}

// ---------------------------------------------------------------------------
// K1 (fused prep): blocks [0,3760) cast x fp32->bf16 (pad rows to NPAD);
//                  blocks [3760,5808) transpose conv_weights -> wt bf16;
//                  blocks [5808,7683) histogram of edge dst.
// ---------------------------------------------------------------------------
__global__ void prep_kernel(const float* __restrict__ x, unsigned short* __restrict__ xbf,
                            const float* __restrict__ cw, unsigned short* __restrict__ wt,
                            const int* __restrict__ edst, int* __restrict__ counts) {
    int b = blockIdx.x;
    if (b < 3760) {
        int t = b * 256 + threadIdx.x;               // 962560 threads, 8 elems each
        int base = t * 8;
        int n = base >> 8;
        unsigned short h[8];
        if (n < N_NODES) {
            float4 a = *(const float4*)(x + base);
            float4 c = *(const float4*)(x + base + 4);
            h[0]=f2bf(a.x); h[1]=f2bf(a.y); h[2]=f2bf(a.z); h[3]=f2bf(a.w);
            h[4]=f2bf(c.x); h[5]=f2bf(c.y); h[6]=f2bf(c.z); h[7]=f2bf(c.w);
        } else {
            #pragma unroll
            for (int i = 0; i < 8; ++i) h[i] = 0;
        }
        uint4 o;
        o.x = (unsigned)h[0] | ((unsigned)h[1] << 16);
        o.y = (unsigned)h[2] | ((unsigned)h[3] << 16);
        o.z = (unsigned)h[4] | ((unsigned)h[5] << 16);
        o.w = (unsigned)h[6] | ((unsigned)h[7] << 16);
        *(uint4*)(xbf + base) = o;
    } else if (b < 5808) {
        int o = (b - 3760) * 256 + threadIdx.x;      // 524288 threads
        int i = o & 255;
        int c = (o >> 8) & 255;
        int r = o >> 16;
        float v = cw[(((size_t)r * 4 + (c >> 6)) * 256 + i) * 64 + (c & 63)];
        wt[o] = f2bf(v);
    } else {
        int e = (b - 5808) * 256 + threadIdx.x;      // 480000 threads
        if (e < N_EDGES) atomicAdd(&counts[edst[e]], 1);
    }
}

// ---------------------------------------------------------------------------
// K2a/b/c: three-phase exclusive scan of counts -> offsets (+cursor copy)
// ---------------------------------------------------------------------------
__global__ void scan1_kernel(const int* __restrict__ counts, int* __restrict__ locexcl,
                             int* __restrict__ bsum) {
    __shared__ int sm[256];
    int tid = threadIdx.x;
    int idx = blockIdx.x * 256 + tid;
    int v = (idx < N_NODES) ? counts[idx] : 0;
    sm[tid] = v;
    __syncthreads();
    for (int o = 1; o < 256; o <<= 1) {
        int t = (tid >= o) ? sm[tid - o] : 0;
        __syncthreads();
        sm[tid] += t;
        __syncthreads();
    }
    int incl = sm[tid];
    if (idx < N_NODES) locexcl[idx] = incl - v;
    if (tid == 255) bsum[blockIdx.x] = incl;
}

__global__ void scan2_kernel(const int* __restrict__ bsum, int* __restrict__ bpre) {
    __shared__ int sm[128];
    int tid = threadIdx.x;
    int v = (tid < NB_SCAN) ? bsum[tid] : 0;
    sm[tid] = v;
    __syncthreads();
    for (int o = 1; o < 128; o <<= 1) {
        int t = (tid >= o) ? sm[tid - o] : 0;
        __syncthreads();
        sm[tid] += t;
        __syncthreads();
    }
    if (tid < NB_SCAN) bpre[tid] = sm[tid] - v;
}

__global__ void scan3_kernel(const int* __restrict__ locexcl, const int* __restrict__ bpre,
                             int* __restrict__ offsets, int* __restrict__ cursor) {
    int idx = blockIdx.x * 256 + threadIdx.x;
    if (idx < N_NODES) {
        int o = bpre[blockIdx.x] + locexcl[idx];
        offsets[idx] = o;
        cursor[idx]  = o;
    }
    if (idx == 0) offsets[N_NODES] = N_EDGES;
}

// ---------------------------------------------------------------------------
// K3: bf16 MFMA GEMM  feat[r][n][c] = sum_k xbf[n][k] * wt[r][c][k]
//     128x128 tile, BK=32, global_load_lds(16B), XOR chunk swizzle on LDS.
//     SWAPPED operand order: mfma(wt_frag, x_frag) -> lane holds 4 CONSECUTIVE
//     feat COLUMNS of one node row per fragment -> ushort4 (8B) stores,
//     no LDS transpose needed.  C-layout (row=quad*4+e, col=l15) HW-verified.
//     Fused epilogue 2: proj via per-wave LDS reduction over quads
//     (NOT lane shuffles — shuffle-butterfly failed on HW, rounds 1 & 4).
// ---------------------------------------------------------------------------
__global__ __launch_bounds__(256) void gemm_kernel(
    const unsigned short* __restrict__ xbf,   // [NPAD][256]
    const unsigned short* __restrict__ wt,    // [R][256][256]
    const float* __restrict__ attn_l,         // [R][4][64]
    const float* __restrict__ attn_r,
    unsigned short* __restrict__ feat,        // [R][NPAD][256]
    float* __restrict__ projl,                // [R][NPAD][4]
    float* __restrict__ projr)
{
    // first 16 KB: A|B staging during K-loop, then proj-L buffers (per-wave 4KB);
    // upper 16 KB: proj-R buffers.
    __shared__ __align__(16) unsigned char smem[32768];

    const int tid  = threadIdx.x;
    const int lane = tid & 63;
    const int w    = tid >> 6;        // wave 0..3
    const int wm   = w >> 1;          // wave node-block (0/1)
    const int wn   = w & 1;           // wave col-block (0/1)
    const int quad = lane >> 4;
    const int l15  = lane & 15;

    const int bid = blockIdx.x;                // 0..3759
    const int mt  = bid >> 4;                  // 0..234  (16 consecutive blocks share A-tile)
    const int r   = (bid >> 1) & 7;            // relation
    const int nt  = bid & 1;                   // col tile (0/1)
    const int mbase = mt * 128;
    const int nbase = nt * 128;

    const unsigned short* Asrc = xbf + (size_t)mbase * 256;
    const unsigned short* Bsrc = wt + ((size_t)r * 256 + nbase) * 256;

    f32x4 acc[4][4] = {};   // acc[i][j]: cols i*16+quad*4+e of node j*16+l15

    // staging: lane's LDS slot L = w*64+lane -> (row srow, chunk c0);
    // holds GLOBAL chunk c0 ^ ((row>>1)&3)  (XOR swizzle)
    const int srow = w * 16 + (lane >> 2);
    const int c0   = lane & 3;

    for (int k0 = 0; k0 < 256; k0 += 32) {
        #pragma unroll
        for (int n = 0; n < 2; ++n) {
            int row = n * 64 + srow;
            int c   = c0 ^ ((row >> 1) & 3);
            load_lds16(Asrc + (size_t)row * 256 + k0 + c * 8, smem + (n * 256 + w * 64) * 16);
        }
        #pragma unroll
        for (int n = 0; n < 2; ++n) {
            int row = n * 64 + srow;
            int c   = c0 ^ ((row >> 1) & 3);
            load_lds16(Bsrc + (size_t)row * 256 + k0 + c * 8, smem + 8192 + (n * 256 + w * 64) * 16);
        }
        __syncthreads();

        bf16x8 xf[4], wf[4];
        #pragma unroll
        for (int j = 0; j < 4; ++j) {          // x rows (node fragments)
            int row = wm * 64 + j * 16 + l15;
            int cc  = quad ^ ((row >> 1) & 3);
            xf[j] = *(const bf16x8*)(smem + row * 64 + cc * 16);
        }
        #pragma unroll
        for (int i = 0; i < 4; ++i) {          // wt rows (col fragments)
            int row = wn * 64 + i * 16 + l15;
            int cc  = quad ^ ((row >> 1) & 3);
            wf[i] = *(const bf16x8*)(smem + 8192 + row * 64 + cc * 16);
        }

        #pragma unroll
        for (int i = 0; i < 4; ++i)
            #pragma unroll
            for (int j = 0; j < 4; ++j)
                acc[i][j] = __builtin_amdgcn_mfma_f32_16x16x32_bf16(wf[i], xf[j], acc[i][j], 0, 0, 0);
        __syncthreads();
    }

    // ---- epilogue 1: feat bf16 via ushort4 stores (4 consecutive cols per lane)
    #pragma unroll
    for (int j = 0; j < 4; ++j) {
        int node = mbase + wm * 64 + j * 16 + l15;
        size_t rowb = ((size_t)r * NPAD + node) * 256 + nbase + wn * 64;
        #pragma unroll
        for (int i = 0; i < 4; ++i) {
            ushort4 v;
            v.x = f2bf(acc[i][j][0]);
            v.y = f2bf(acc[i][j][1]);
            v.z = f2bf(acc[i][j][2]);
            v.w = f2bf(acc[i][j][3]);
            *(ushort4*)(feat + rowb + i * 16 + quad * 4) = v;
        }
    }

    // ---- epilogue 2: fused attention projections.
    // lane's partial for node j*16+l15 covers cols {i*16+quad*4+e}; reduce
    // over quads via per-wave LDS buffer (stride 5 -> max 2-way banks, free).
    const int head = nt * 2 + wn;
    float alv[4][4], arv[4][4];
    #pragma unroll
    for (int i = 0; i < 4; ++i)
        #pragma unroll
        for (int e = 0; e < 4; ++e) {
            int c = i * 16 + quad * 4 + e;
            alv[i][e] = attn_l[((size_t)r * 4 + head) * 64 + c];
            arv[i][e] = attn_r[((size_t)r * 4 + head) * 64 + c];
        }
    float* bufL = (float*)smem + w * 1024;            // uses 320 floats of 1024
    float* bufR = (float*)(smem + 16384) + w * 1024;
    #pragma unroll
    for (int j = 0; j < 4; ++j) {
        float s1 = 0.f, s2 = 0.f;
        #pragma unroll
        for (int i = 0; i < 4; ++i)
            #pragma unroll
            for (int e = 0; e < 4; ++e) {
                s1 += acc[i][j][e] * alv[i][e];
                s2 += acc[i][j][e] * arv[i][e];
            }
        int node = j * 16 + l15;                      // 0..63 within wave
        bufL[node * 5 + quad] = s1;
        bufR[node * 5 + quad] = s2;
    }
    // lane reduces node == lane (in-wave DS ordering guarantees visibility)
    float sL = 0.f, sR = 0.f;
    #pragma unroll
    for (int q = 0; q < 4; ++q) {
        sL += bufL[lane * 5 + q];
        sR += bufR[lane * 5 + q];
    }
    int g = mbase + wm * 64 + lane;
    projl[((size_t)r * NPAD + g) * 4 + head] = sL;
    projr[((size_t)r * NPAD + g) * 4 + head] = sR;
}

// ---------------------------------------------------------------------------
// K4: fused per-edge logits + CSR scatter with payload:
//     srcoff[p] = t*NPAD+s  and  exw[p] = float4 of exp(leaky_relu(el+er))
// ---------------------------------------------------------------------------
__global__ void logits_scatter_kernel(
    const int* __restrict__ esrc, const int* __restrict__ edst, const int* __restrict__ etyp,
    const float* __restrict__ projl, const float* __restrict__ projr,
    int* __restrict__ cursor, int* __restrict__ srcoff, float* __restrict__ exw)
{
    int e = blockIdx.x * 256 + threadIdx.x;
    if (e >= N_EDGES) return;
    int s = esrc[e], d = edst[e], t = etyp[e];
    float4 pl = ((const float4*)projl)[(size_t)t * NPAD + s];
    float4 pr = ((const float4*)projr)[(size_t)t * NPAD + d];
    float4 o;
    float v;
    v = pl.x + pr.x; v = v > 0.f ? v : 0.2f * v; o.x = __expf(v);
    v = pl.y + pr.y; v = v > 0.f ? v : 0.2f * v; o.y = __expf(v);
    v = pl.z + pr.z; v = v > 0.f ? v : 0.2f * v; o.z = __expf(v);
    v = pl.w + pr.w; v = v > 0.f ? v : 0.2f * v; o.w = __expf(v);
    int p = atomicAdd(&cursor[d], 1);
    srcoff[p] = t * NPAD + s;
    ((float4*)exw)[p] = o;
}

// ---------------------------------------------------------------------------
// K5: per-node aggregation: one wave per dst node (4 nodes / block).
//     Streams srcoff/exw; 8/4/2 independent feat gathers in flight.
// ---------------------------------------------------------------------------
__global__ __launch_bounds__(256) void aggregate_kernel(
    const int* __restrict__ offsets, const int* __restrict__ srcoff,
    const float* __restrict__ exw, const unsigned short* __restrict__ feat,
    const float* __restrict__ bias, float* __restrict__ out)
{
    int v = blockIdx.x * 4 + (threadIdx.x >> 6);   // grid 7500 -> v < 30000
    int lane = threadIdx.x & 63;
    int head = lane >> 4;
    int s0 = offsets[v], s1 = offsets[v + 1];
    float a0 = 0.f, a1 = 0.f, a2 = 0.f, a3 = 0.f, den = 0.f;
    int i = s0;
    for (; i + 8 <= s1; i += 8) {
        int o[8]; float ee[8]; ushort4 ff[8];
        #pragma unroll
        for (int u = 0; u < 8; ++u) { o[u] = srcoff[i + u]; ee[u] = exw[(size_t)(i + u) * 4 + head]; }
        #pragma unroll
        for (int u = 0; u < 8; ++u) ff[u] = *(const ushort4*)(feat + (size_t)o[u] * 256 + lane * 4);
        #pragma unroll
        for (int u = 0; u < 8; ++u) {
            den += ee[u];
            a0 += ee[u] * bf2f(ff[u].x);
            a1 += ee[u] * bf2f(ff[u].y);
            a2 += ee[u] * bf2f(ff[u].z);
            a3 += ee[u] * bf2f(ff[u].w);
        }
    }
    for (; i + 4 <= s1; i += 4) {
        int o[4]; float ee[4]; ushort4 ff[4];
        #pragma unroll
        for (int u = 0; u < 4; ++u) { o[u] = srcoff[i + u]; ee[u] = exw[(size_t)(i + u) * 4 + head]; }
        #pragma unroll
        for (int u = 0; u < 4; ++u) ff[u] = *(const ushort4*)(feat + (size_t)o[u] * 256 + lane * 4);
        #pragma unroll
        for (int u = 0; u < 4; ++u) {
            den += ee[u];
            a0 += ee[u] * bf2f(ff[u].x);
            a1 += ee[u] * bf2f(ff[u].y);
            a2 += ee[u] * bf2f(ff[u].z);
            a3 += ee[u] * bf2f(ff[u].w);
        }
    }
    for (; i + 2 <= s1; i += 2) {
        int o[2]; float ee[2]; ushort4 ff[2];
        #pragma unroll
        for (int u = 0; u < 2; ++u) { o[u] = srcoff[i + u]; ee[u] = exw[(size_t)(i + u) * 4 + head]; }
        #pragma unroll
        for (int u = 0; u < 2; ++u) ff[u] = *(const ushort4*)(feat + (size_t)o[u] * 256 + lane * 4);
        #pragma unroll
        for (int u = 0; u < 2; ++u) {
            den += ee[u];
            a0 += ee[u] * bf2f(ff[u].x);
            a1 += ee[u] * bf2f(ff[u].y);
            a2 += ee[u] * bf2f(ff[u].z);
            a3 += ee[u] * bf2f(ff[u].w);
        }
    }
    if (i < s1) {
        int o0 = srcoff[i];
        float e0 = exw[(size_t)i * 4 + head];
        ushort4 f0 = *(const ushort4*)(feat + (size_t)o0 * 256 + lane * 4);
        den += e0;
        a0 += e0 * bf2f(f0.x);
        a1 += e0 * bf2f(f0.y);
        a2 += e0 * bf2f(f0.z);
        a3 += e0 * bf2f(f0.w);
    }
    float inv = den > 0.f ? 1.f / den : 0.f;
    float4 o;
    o.x = a0 * inv + bias[lane * 4 + 0];
    o.y = a1 * inv + bias[lane * 4 + 1];
    o.z = a2 * inv + bias[lane * 4 + 2];
    o.w = a3 * inv + bias[lane * 4 + 3];
    ((float4*)out)[(size_t)v * 64 + lane] = o;
}

// ---------------------------------------------------------------------------
extern "C" void kernel_launch(void* const* d_in, const int* in_sizes, int n_in,
                              void* d_out, int out_size, void* d_ws, size_t ws_size,
                              hipStream_t stream) {
    const float* x    = (const float*)d_in[0];
    const float* cw   = (const float*)d_in[1];
    const float* al   = (const float*)d_in[2];
    const float* ar   = (const float*)d_in[3];
    const float* bias = (const float*)d_in[4];
    const int* esrc   = (const int*)d_in[5];
    const int* edst   = (const int*)d_in[6];
    const int* etyp   = (const int*)d_in[7];
    float* out        = (float*)d_out;

    char* ws = (char*)d_ws;
    size_t off = 0;
    auto alloc = [&](size_t bytes) { size_t o = off; off += (bytes + 255) & ~(size_t)255; return o; };

    unsigned short* xbf  = (unsigned short*)(ws + alloc((size_t)NPAD * 256 * 2));          // 15.4 MB
    unsigned short* wt   = (unsigned short*)(ws + alloc((size_t)N_RELS * 256 * 256 * 2));  // 1 MB
    unsigned short* feat = (unsigned short*)(ws + alloc((size_t)N_RELS * NPAD * 256 * 2)); // 123.2 MB
    float* projl = (float*)(ws + alloc((size_t)N_RELS * NPAD * 4 * 4));                    // 3.85 MB
    float* projr = (float*)(ws + alloc((size_t)N_RELS * NPAD * 4 * 4));                    // 3.85 MB
    float* exw   = (float*)(ws + alloc((size_t)N_EDGES * 4 * 4));                          // 7.68 MB
    int* srcoff  = (int*)(ws + alloc((size_t)N_EDGES * 4));                                // 1.92 MB
    int* counts  = (int*)(ws + alloc((size_t)N_NODES * 4));
    int* offsets = (int*)(ws + alloc((size_t)(N_NODES + 1) * 4));
    int* cursor  = (int*)(ws + alloc((size_t)N_NODES * 4));
    int* locexcl = (int*)(ws + alloc((size_t)N_NODES * 4));
    int* bsum    = (int*)(ws + alloc((size_t)NB_SCAN * 4));
    int* bpre    = (int*)(ws + alloc((size_t)NB_SCAN * 4));

    hipMemsetAsync(counts, 0, (size_t)N_NODES * 4, stream);

    prep_kernel<<<7683, 256, 0, stream>>>(x, xbf, cw, wt, edst, counts);
    scan1_kernel<<<NB_SCAN, 256, 0, stream>>>(counts, locexcl, bsum);
    scan2_kernel<<<1, 128, 0, stream>>>(bsum, bpre);
    scan3_kernel<<<NB_SCAN, 256, 0, stream>>>(locexcl, bpre, offsets, cursor);
    gemm_kernel<<<3760, 256, 0, stream>>>(xbf, wt, al, ar, feat, projl, projr);
    logits_scatter_kernel<<<1875, 256, 0, stream>>>(esrc, edst, etyp, projl, projr,
                                                    cursor, srcoff, exw);
    aggregate_kernel<<<7500, 256, 0, stream>>>(offsets, srcoff, exw, feat, bias, out);
}

// Round 8
// 258.238 us; speedup vs baseline: 1.0100x; 1.0100x over previous
//
#include <hip/hip_runtime.h>
#include <hip/hip_bf16.h>

// Problem constants
#define N_NODES 30000
#define NPAD    30080            // 235 * 128
#define N_EDGES 480000
#define N_RELS  8
#define NB_SCAN 118              // ceil(30000/256)

typedef short bf16x8 __attribute__((ext_vector_type(8)));
typedef float f32x4  __attribute__((ext_vector_type(4)));

__device__ __forceinline__ unsigned short f2bf(float f) {
    unsigned u = __float_as_uint(f);
    u += 0x7fffu + ((u >> 16) & 1u);     // round-to-nearest-even
    return (unsigned short)(u >> 16);
}
__device__ __forceinline__ float bf2f(unsigned short h) {
    return __uint_as_float(((unsigned)h) << 16);
}
__device__ __forceinline__ ushort2 pk2bf(float a, float b) {  // v_cvt_pk_bf16_f32 (RNE)
    __hip_bfloat162 t = __float22bfloat162_rn(float2{a, b});
    union { __hip_bfloat162 h; ushort2 u; } cv; cv.h = t; return cv.u;
}

__device__ __forceinline__ void load_lds16(const void* g, void* l) {
    __builtin_amdgcn_global_load_lds(
        (const __attribute__((address_space(1))) unsigned int*)g,
        (__attribute__((address_space(3))) unsigned int*)l,
        16, 0, 0);
}

// ---------------------------------------------------------------------------
// K1 (fused prep): blocks [0,3760) cast x fp32->bf16 (pad rows to NPAD);
//                  blocks [3760,5808) transpose conv_weights -> wt bf16;
//                  blocks [5808,7683) histogram of edge dst.
// ---------------------------------------------------------------------------
__global__ void prep_kernel(const float* __restrict__ x, unsigned short* __restrict__ xbf,
                            const float* __restrict__ cw, unsigned short* __restrict__ wt,
                            const int* __restrict__ edst, int* __restrict__ counts) {
    int b = blockIdx.x;
    if (b < 3760) {
        int t = b * 256 + threadIdx.x;               // 962560 threads, 8 elems each
        int base = t * 8;
        int n = base >> 8;
        unsigned short h[8];
        if (n < N_NODES) {
            float4 a = *(const float4*)(x + base);
            float4 c = *(const float4*)(x + base + 4);
            h[0]=f2bf(a.x); h[1]=f2bf(a.y); h[2]=f2bf(a.z); h[3]=f2bf(a.w);
            h[4]=f2bf(c.x); h[5]=f2bf(c.y); h[6]=f2bf(c.z); h[7]=f2bf(c.w);
        } else {
            #pragma unroll
            for (int i = 0; i < 8; ++i) h[i] = 0;
        }
        uint4 o;
        o.x = (unsigned)h[0] | ((unsigned)h[1] << 16);
        o.y = (unsigned)h[2] | ((unsigned)h[3] << 16);
        o.z = (unsigned)h[4] | ((unsigned)h[5] << 16);
        o.w = (unsigned)h[6] | ((unsigned)h[7] << 16);
        *(uint4*)(xbf + base) = o;
    } else if (b < 5808) {
        int o = (b - 3760) * 256 + threadIdx.x;      // 524288 threads
        int i = o & 255;
        int c = (o >> 8) & 255;
        int r = o >> 16;
        float v = cw[(((size_t)r * 4 + (c >> 6)) * 256 + i) * 64 + (c & 63)];
        wt[o] = f2bf(v);
    } else {
        int e = (b - 5808) * 256 + threadIdx.x;      // 480000 threads
        if (e < N_EDGES) atomicAdd(&counts[edst[e]], 1);
    }
}

// ---------------------------------------------------------------------------
// K2a/b/c: three-phase exclusive scan of counts -> offsets (+cursor copy)
// ---------------------------------------------------------------------------
__global__ void scan1_kernel(const int* __restrict__ counts, int* __restrict__ locexcl,
                             int* __restrict__ bsum) {
    __shared__ int sm[256];
    int tid = threadIdx.x;
    int idx = blockIdx.x * 256 + tid;
    int v = (idx < N_NODES) ? counts[idx] : 0;
    sm[tid] = v;
    __syncthreads();
    for (int o = 1; o < 256; o <<= 1) {
        int t = (tid >= o) ? sm[tid - o] : 0;
        __syncthreads();
        sm[tid] += t;
        __syncthreads();
    }
    int incl = sm[tid];
    if (idx < N_NODES) locexcl[idx] = incl - v;
    if (tid == 255) bsum[blockIdx.x] = incl;
}

__global__ void scan2_kernel(const int* __restrict__ bsum, int* __restrict__ bpre) {
    __shared__ int sm[128];
    int tid = threadIdx.x;
    int v = (tid < NB_SCAN) ? bsum[tid] : 0;
    sm[tid] = v;
    __syncthreads();
    for (int o = 1; o < 128; o <<= 1) {
        int t = (tid >= o) ? sm[tid - o] : 0;
        __syncthreads();
        sm[tid] += t;
        __syncthreads();
    }
    if (tid < NB_SCAN) bpre[tid] = sm[tid] - v;
}

__global__ void scan3_kernel(const int* __restrict__ locexcl, const int* __restrict__ bpre,
                             int* __restrict__ offsets, int* __restrict__ cursor) {
    int idx = blockIdx.x * 256 + threadIdx.x;
    if (idx < N_NODES) {
        int o = bpre[blockIdx.x] + locexcl[idx];
        offsets[idx] = o;
        cursor[idx]  = o;
    }
    if (idx == 0) offsets[N_NODES] = N_EDGES;
}

// ---------------------------------------------------------------------------
// K3: bf16 MFMA GEMM  feat[r][n][c] = sum_k xbf[n][k] * wt[r][c][k]
//     128x128 tile, BK=32, global_load_lds(16B), XOR chunk swizzle.
//     Swapped operand order: mfma(wt_frag, x_frag) -> ushort4 col stores.
//     XCD-locality remap: work = (bid&7)*470 + (bid>>3) — blocks with equal
//     bid%8 (same XCD, round-robin dispatch) get a contiguous work range so
//     each A-tile's 16 consumers run on ONE XCD with the tile L2-resident.
//     Fused epilogue 2: proj via per-wave LDS reduction over quads
//     (NOT lane shuffles — shuffle-butterfly failed on HW, rounds 1 & 4).
// ---------------------------------------------------------------------------
__global__ __launch_bounds__(256) void gemm_kernel(
    const unsigned short* __restrict__ xbf,   // [NPAD][256]
    const unsigned short* __restrict__ wt,    // [R][256][256]
    const float* __restrict__ attn_l,         // [R][4][64]
    const float* __restrict__ attn_r,
    unsigned short* __restrict__ feat,        // [R][NPAD][256]
    float* __restrict__ projl,                // [R][NPAD][4]
    float* __restrict__ projr)
{
    __shared__ __align__(16) unsigned char smem[32768];

    const int tid  = threadIdx.x;
    const int lane = tid & 63;
    const int w    = tid >> 6;        // wave 0..3
    const int wm   = w >> 1;          // wave node-block (0/1)
    const int wn   = w & 1;           // wave col-block (0/1)
    const int quad = lane >> 4;
    const int l15  = lane & 15;

    const int bid  = blockIdx.x;               // 0..3759
    const int work = (bid & 7) * 470 + (bid >> 3);
    const int mt   = work >> 4;                // 0..234
    const int r    = (work >> 1) & 7;          // relation
    const int nt   = work & 1;                 // col tile (0/1)
    const int mbase = mt * 128;
    const int nbase = nt * 128;

    const unsigned short* Asrc = xbf + (size_t)mbase * 256;
    const unsigned short* Bsrc = wt + ((size_t)r * 256 + nbase) * 256;

    f32x4 acc[4][4] = {};   // acc[i][j]: cols i*16+quad*4+e of node j*16+l15

    const int srow = w * 16 + (lane >> 2);
    const int c0   = lane & 3;

    for (int k0 = 0; k0 < 256; k0 += 32) {
        #pragma unroll
        for (int n = 0; n < 2; ++n) {
            int row = n * 64 + srow;
            int c   = c0 ^ ((row >> 1) & 3);
            load_lds16(Asrc + (size_t)row * 256 + k0 + c * 8, smem + (n * 256 + w * 64) * 16);
        }
        #pragma unroll
        for (int n = 0; n < 2; ++n) {
            int row = n * 64 + srow;
            int c   = c0 ^ ((row >> 1) & 3);
            load_lds16(Bsrc + (size_t)row * 256 + k0 + c * 8, smem + 8192 + (n * 256 + w * 64) * 16);
        }
        __syncthreads();

        bf16x8 xf[4], wf[4];
        #pragma unroll
        for (int j = 0; j < 4; ++j) {          // x rows (node fragments)
            int row = wm * 64 + j * 16 + l15;
            int cc  = quad ^ ((row >> 1) & 3);
            xf[j] = *(const bf16x8*)(smem + row * 64 + cc * 16);
        }
        #pragma unroll
        for (int i = 0; i < 4; ++i) {          // wt rows (col fragments)
            int row = wn * 64 + i * 16 + l15;
            int cc  = quad ^ ((row >> 1) & 3);
            wf[i] = *(const bf16x8*)(smem + 8192 + row * 64 + cc * 16);
        }

        #pragma unroll
        for (int i = 0; i < 4; ++i)
            #pragma unroll
            for (int j = 0; j < 4; ++j)
                acc[i][j] = __builtin_amdgcn_mfma_f32_16x16x32_bf16(wf[i], xf[j], acc[i][j], 0, 0, 0);
        __syncthreads();
    }

    // ---- epilogue 1: feat bf16 via packed cvt + ushort4 stores
    #pragma unroll
    for (int j = 0; j < 4; ++j) {
        int node = mbase + wm * 64 + j * 16 + l15;
        size_t rowb = ((size_t)r * NPAD + node) * 256 + nbase + wn * 64;
        #pragma unroll
        for (int i = 0; i < 4; ++i) {
            ushort2 lo = pk2bf(acc[i][j][0], acc[i][j][1]);
            ushort2 hi = pk2bf(acc[i][j][2], acc[i][j][3]);
            ushort4 v;
            v.x = lo.x; v.y = lo.y; v.z = hi.x; v.w = hi.y;
            *(ushort4*)(feat + rowb + i * 16 + quad * 4) = v;
        }
    }

    // ---- epilogue 2: fused attention projections, per-wave LDS reduction
    const int head = nt * 2 + wn;
    float alv[4][4], arv[4][4];
    #pragma unroll
    for (int i = 0; i < 4; ++i)
        #pragma unroll
        for (int e = 0; e < 4; ++e) {
            int c = i * 16 + quad * 4 + e;
            alv[i][e] = attn_l[((size_t)r * 4 + head) * 64 + c];
            arv[i][e] = attn_r[((size_t)r * 4 + head) * 64 + c];
        }
    float* bufL = (float*)smem + w * 1024;
    float* bufR = (float*)(smem + 16384) + w * 1024;
    #pragma unroll
    for (int j = 0; j < 4; ++j) {
        float s1 = 0.f, s2 = 0.f;
        #pragma unroll
        for (int i = 0; i < 4; ++i)
            #pragma unroll
            for (int e = 0; e < 4; ++e) {
                s1 += acc[i][j][e] * alv[i][e];
                s2 += acc[i][j][e] * arv[i][e];
            }
        int node = j * 16 + l15;                      // 0..63 within wave
        bufL[node * 5 + quad] = s1;
        bufR[node * 5 + quad] = s2;
    }
    float sL = 0.f, sR = 0.f;
    #pragma unroll
    for (int q = 0; q < 4; ++q) {
        sL += bufL[lane * 5 + q];
        sR += bufR[lane * 5 + q];
    }
    int g = mbase + wm * 64 + lane;
    projl[((size_t)r * NPAD + g) * 4 + head] = sL;
    projr[((size_t)r * NPAD + g) * 4 + head] = sR;
}

// ---------------------------------------------------------------------------
// K4: fused per-edge logits + CSR scatter with payload:
//     srcoff[p] = t*NPAD+s  and  exw[p] = float4 of exp(leaky_relu(el+er))
// ---------------------------------------------------------------------------
__global__ void logits_scatter_kernel(
    const int* __restrict__ esrc, const int* __restrict__ edst, const int* __restrict__ etyp,
    const float* __restrict__ projl, const float* __restrict__ projr,
    int* __restrict__ cursor, int* __restrict__ srcoff, float* __restrict__ exw)
{
    int e = blockIdx.x * 256 + threadIdx.x;
    if (e >= N_EDGES) return;
    int s = esrc[e], d = edst[e], t = etyp[e];
    float4 pl = ((const float4*)projl)[(size_t)t * NPAD + s];
    float4 pr = ((const float4*)projr)[(size_t)t * NPAD + d];
    float4 o;
    float v;
    v = pl.x + pr.x; v = v > 0.f ? v : 0.2f * v; o.x = __expf(v);
    v = pl.y + pr.y; v = v > 0.f ? v : 0.2f * v; o.y = __expf(v);
    v = pl.z + pr.z; v = v > 0.f ? v : 0.2f * v; o.z = __expf(v);
    v = pl.w + pr.w; v = v > 0.f ? v : 0.2f * v; o.w = __expf(v);
    int p = atomicAdd(&cursor[d], 1);
    srcoff[p] = t * NPAD + s;
    ((float4*)exw)[p] = o;
}

// ---------------------------------------------------------------------------
// K5: per-node aggregation: TWO waves per dst node (2 nodes / 256-thr block),
//     each wave takes half the edge range (halved latency chain, 60k waves),
//     partials combined through LDS; 8/4/2/1-deep independent feat gathers.
// ---------------------------------------------------------------------------
__global__ __launch_bounds__(256) void aggregate_kernel(
    const int* __restrict__ offsets, const int* __restrict__ srcoff,
    const float* __restrict__ exw, const unsigned short* __restrict__ feat,
    const float* __restrict__ bias, float* __restrict__ out)
{
    __shared__ float sm[2][64][5];
    int wid  = threadIdx.x >> 6;      // 0..3
    int slot = wid >> 1;              // node slot in block (0/1)
    int half = wid & 1;               // which half of the edge range
    int v = blockIdx.x * 2 + slot;    // grid 15000 -> v < 30000
    int lane = threadIdx.x & 63;
    int head = lane >> 4;
    int s0 = offsets[v], s1 = offsets[v + 1];
    int mid = s0 + ((s1 - s0 + 1) >> 1);
    int lo = half ? mid : s0;
    int hi = half ? s1  : mid;
    float a0 = 0.f, a1 = 0.f, a2 = 0.f, a3 = 0.f, den = 0.f;
    int i = lo;
    for (; i + 8 <= hi; i += 8) {
        int o[8]; float ee[8]; ushort4 ff[8];
        #pragma unroll
        for (int u = 0; u < 8; ++u) { o[u] = srcoff[i + u]; ee[u] = exw[(size_t)(i + u) * 4 + head]; }
        #pragma unroll
        for (int u = 0; u < 8; ++u) ff[u] = *(const ushort4*)(feat + (size_t)o[u] * 256 + lane * 4);
        #pragma unroll
        for (int u = 0; u < 8; ++u) {
            den += ee[u];
            a0 += ee[u] * bf2f(ff[u].x);
            a1 += ee[u] * bf2f(ff[u].y);
            a2 += ee[u] * bf2f(ff[u].z);
            a3 += ee[u] * bf2f(ff[u].w);
        }
    }
    for (; i + 4 <= hi; i += 4) {
        int o[4]; float ee[4]; ushort4 ff[4];
        #pragma unroll
        for (int u = 0; u < 4; ++u) { o[u] = srcoff[i + u]; ee[u] = exw[(size_t)(i + u) * 4 + head]; }
        #pragma unroll
        for (int u = 0; u < 4; ++u) ff[u] = *(const ushort4*)(feat + (size_t)o[u] * 256 + lane * 4);
        #pragma unroll
        for (int u = 0; u < 4; ++u) {
            den += ee[u];
            a0 += ee[u] * bf2f(ff[u].x);
            a1 += ee[u] * bf2f(ff[u].y);
            a2 += ee[u] * bf2f(ff[u].z);
            a3 += ee[u] * bf2f(ff[u].w);
        }
    }
    for (; i + 2 <= hi; i += 2) {
        int o[2]; float ee[2]; ushort4 ff[2];
        #pragma unroll
        for (int u = 0; u < 2; ++u) { o[u] = srcoff[i + u]; ee[u] = exw[(size_t)(i + u) * 4 + head]; }
        #pragma unroll
        for (int u = 0; u < 2; ++u) ff[u] = *(const ushort4*)(feat + (size_t)o[u] * 256 + lane * 4);
        #pragma unroll
        for (int u = 0; u < 2; ++u) {
            den += ee[u];
            a0 += ee[u] * bf2f(ff[u].x);
            a1 += ee[u] * bf2f(ff[u].y);
            a2 += ee[u] * bf2f(ff[u].z);
            a3 += ee[u] * bf2f(ff[u].w);
        }
    }
    if (i < hi) {
        int o0 = srcoff[i];
        float e0 = exw[(size_t)i * 4 + head];
        ushort4 f0 = *(const ushort4*)(feat + (size_t)o0 * 256 + lane * 4);
        den += e0;
        a0 += e0 * bf2f(f0.x);
        a1 += e0 * bf2f(f0.y);
        a2 += e0 * bf2f(f0.z);
        a3 += e0 * bf2f(f0.w);
    }
    if (half) {
        sm[slot][lane][0] = a0; sm[slot][lane][1] = a1;
        sm[slot][lane][2] = a2; sm[slot][lane][3] = a3;
        sm[slot][lane][4] = den;
    }
    __syncthreads();
    if (!half) {
        a0 += sm[slot][lane][0]; a1 += sm[slot][lane][1];
        a2 += sm[slot][lane][2]; a3 += sm[slot][lane][3];
        den += sm[slot][lane][4];
        float inv = den > 0.f ? 1.f / den : 0.f;
        float4 o;
        o.x = a0 * inv + bias[lane * 4 + 0];
        o.y = a1 * inv + bias[lane * 4 + 1];
        o.z = a2 * inv + bias[lane * 4 + 2];
        o.w = a3 * inv + bias[lane * 4 + 3];
        ((float4*)out)[(size_t)v * 64 + lane] = o;
    }
}

// ---------------------------------------------------------------------------
extern "C" void kernel_launch(void* const* d_in, const int* in_sizes, int n_in,
                              void* d_out, int out_size, void* d_ws, size_t ws_size,
                              hipStream_t stream) {
    const float* x    = (const float*)d_in[0];
    const float* cw   = (const float*)d_in[1];
    const float* al   = (const float*)d_in[2];
    const float* ar   = (const float*)d_in[3];
    const float* bias = (const float*)d_in[4];
    const int* esrc   = (const int*)d_in[5];
    const int* edst   = (const int*)d_in[6];
    const int* etyp   = (const int*)d_in[7];
    float* out        = (float*)d_out;

    char* ws = (char*)d_ws;
    size_t off = 0;
    auto alloc = [&](size_t bytes) { size_t o = off; off += (bytes + 255) & ~(size_t)255; return o; };

    unsigned short* xbf  = (unsigned short*)(ws + alloc((size_t)NPAD * 256 * 2));          // 15.4 MB
    unsigned short* wt   = (unsigned short*)(ws + alloc((size_t)N_RELS * 256 * 256 * 2));  // 1 MB
    unsigned short* feat = (unsigned short*)(ws + alloc((size_t)N_RELS * NPAD * 256 * 2)); // 123.2 MB
    float* projl = (float*)(ws + alloc((size_t)N_RELS * NPAD * 4 * 4));                    // 3.85 MB
    float* projr = (float*)(ws + alloc((size_t)N_RELS * NPAD * 4 * 4));                    // 3.85 MB
    float* exw   = (float*)(ws + alloc((size_t)N_EDGES * 4 * 4));                          // 7.68 MB
    int* srcoff  = (int*)(ws + alloc((size_t)N_EDGES * 4));                                // 1.92 MB
    int* counts  = (int*)(ws + alloc((size_t)N_NODES * 4));
    int* offsets = (int*)(ws + alloc((size_t)(N_NODES + 1) * 4));
    int* cursor  = (int*)(ws + alloc((size_t)N_NODES * 4));
    int* locexcl = (int*)(ws + alloc((size_t)N_NODES * 4));
    int* bsum    = (int*)(ws + alloc((size_t)NB_SCAN * 4));
    int* bpre    = (int*)(ws + alloc((size_t)NB_SCAN * 4));

    hipMemsetAsync(counts, 0, (size_t)N_NODES * 4, stream);

    prep_kernel<<<7683, 256, 0, stream>>>(x, xbf, cw, wt, edst, counts);
    scan1_kernel<<<NB_SCAN, 256, 0, stream>>>(counts, locexcl, bsum);
    scan2_kernel<<<1, 128, 0, stream>>>(bsum, bpre);
    scan3_kernel<<<NB_SCAN, 256, 0, stream>>>(locexcl, bpre, offsets, cursor);
    gemm_kernel<<<3760, 256, 0, stream>>>(xbf, wt, al, ar, feat, projl, projr);
    logits_scatter_kernel<<<1875, 256, 0, stream>>>(esrc, edst, etyp, projl, projr,
                                                    cursor, srcoff, exw);
    aggregate_kernel<<<15000, 256, 0, stream>>>(offsets, srcoff, exw, feat, bias, out);
}